// Round 1
// baseline (1069.638 us; speedup 1.0000x reference)
//
#include <hip/hip_runtime.h>
#include <cstdint>
#include <cstddef>

// AnimaMLP: router(top-5 of 8, softmax/e) + 8 dense experts (silu(xWg)*xWu)Wd,
// signed-weighted sum, plus mean(output^2) scalar.
//
// Strategy:
//   c[t,e] = router_weight * sign  (fp32, exact semantics)
//   H'[t, e*1024+i] = c[t,e] * silu(g) * u   (bf16, via fused dual-GEMM1)
//   output = H' @ Wd_flat                    (GEMM2, K=8192)
//   d_out[16777216] = mean(output^2)
//
// ws map (bytes):
//   0         Xb   bf16 8192x2048   33,554,432
//   33554432  Wgt  bf16 8x1024x2048 33,554,432   (Wg^T per expert, k-contig)
//   67108864  Wut  bf16             33,554,432
//   100663296 Wdt  bf16 2048x8192   33,554,432   (Wd^T, k-contig)
//   134217728 H'   bf16 4096x8192   67,108,864   (one M-chunk at a time)
//   201326592 Cw   f32  8192x8         262,144
//   201588736 part f32  1024             4,096
// total ~201.6 MB

typedef short bf16x8 __attribute__((ext_vector_type(8)));
typedef float f32x4 __attribute__((ext_vector_type(4)));
typedef unsigned short u16;

typedef const unsigned int __attribute__((address_space(1)))* as1_u32p;
typedef unsigned int __attribute__((address_space(3)))* as3_u32p;

__device__ __forceinline__ u16 f2bf(float f) {
  unsigned u = __builtin_bit_cast(unsigned, f);
  u += 0x7fffu + ((u >> 16) & 1u);   // round-to-nearest-even
  return (u16)(u >> 16);
}

__device__ __forceinline__ void gload16(const void* g, const u16* lds) {
  as1_u32p gp = (as1_u32p)(uintptr_t)g;
  as3_u32p lp = (as3_u32p)(unsigned)(uintptr_t)lds;
  __builtin_amdgcn_global_load_lds(gp, lp, 16, 0, 0);
}

// ---------------- router + x->bf16 ----------------
__global__ __launch_bounds__(256) void router_kernel(
    const float* __restrict__ x, const float* __restrict__ Wr,
    float* __restrict__ Cw, u16* __restrict__ Xb) {
  const int l = threadIdx.x & 63;
  const int t = blockIdx.x * 4 + (threadIdx.x >> 6);
  const float* xr = x + (size_t)t * 2048;
  u16* xbr = Xb + (size_t)t * 2048;
  float p[8] = {0.f,0.f,0.f,0.f,0.f,0.f,0.f,0.f};
#pragma unroll
  for (int it = 0; it < 8; ++it) {
    const int d0 = it * 256 + l * 4;
    const float4 xv = *(const float4*)(xr + d0);
    unsigned lo = (unsigned)f2bf(xv.x) | ((unsigned)f2bf(xv.y) << 16);
    unsigned hi = (unsigned)f2bf(xv.z) | ((unsigned)f2bf(xv.w) << 16);
    *(unsigned*)(xbr + d0) = lo;
    *(unsigned*)(xbr + d0 + 2) = hi;
    const float xs[4] = {xv.x, xv.y, xv.z, xv.w};
#pragma unroll
    for (int jj = 0; jj < 4; ++jj) {
      const float4 w0 = *(const float4*)(Wr + (size_t)(d0 + jj) * 8);
      const float4 w1 = *(const float4*)(Wr + (size_t)(d0 + jj) * 8 + 4);
      p[0] += xs[jj] * w0.x; p[1] += xs[jj] * w0.y;
      p[2] += xs[jj] * w0.z; p[3] += xs[jj] * w0.w;
      p[4] += xs[jj] * w1.x; p[5] += xs[jj] * w1.y;
      p[6] += xs[jj] * w1.z; p[7] += xs[jj] * w1.w;
    }
  }
#pragma unroll
  for (int e = 0; e < 8; ++e) {
    float v = p[e];
#pragma unroll
    for (int off = 32; off > 0; off >>= 1) v += __shfl_xor(v, off, 64);
    p[e] = v;
  }
  constexpr float INV_TEMP = 0.36787944117144233f;  // 1/e
  float mx = -1e30f;
#pragma unroll
  for (int e = 0; e < 8; ++e) { p[e] *= INV_TEMP; mx = fmaxf(mx, p[e]); }
  float sum = 0.f;
#pragma unroll
  for (int e = 0; e < 8; ++e) { p[e] = __expf(p[e] - mx); sum += p[e]; }
  const float inv_sum = 1.f / sum;
#pragma unroll
  for (int e = 0; e < 8; ++e) p[e] *= inv_sum;
  // drop the 3 smallest probs (ties: drop higher index, matching top_k)
  unsigned sel = 0xFFu;
  for (int it = 0; it < 3; ++it) {
    float mn = 1e30f; int mi = 0;
#pragma unroll
    for (int e = 0; e < 8; ++e)
      if ((sel >> e) & 1u) { if (p[e] <= mn) { mn = p[e]; mi = e; } }
    sel &= ~(1u << mi);
  }
  float wsum = 0.f;
#pragma unroll
  for (int e = 0; e < 8; ++e) if ((sel >> e) & 1u) wsum += p[e];
  const float inv_w = 1.f / (wsum + 1e-8f);
  if (l == 0) {
#pragma unroll
    for (int e = 0; e < 8; ++e) {
      float v = ((sel >> e) & 1u) ? p[e] * inv_w : 0.f;
      Cw[(size_t)t * 8 + e] = (e < 4) ? v : -v;
    }
  }
}

// ---------------- transpose + fp32->bf16 ----------------
// out[z*ZO + c*CS + r] = bf16(in[z*R*C + r*C + c])
__global__ __launch_bounds__(256) void tcvt_kernel(
    const float* __restrict__ in, u16* __restrict__ out,
    int R, int C, long long ZO, long long CS) {
  __shared__ float tile[32][33];
  const int z = blockIdx.z;
  const float* ib = in + (size_t)z * R * C;
  const int r0 = blockIdx.y * 32, c0 = blockIdx.x * 32;
  const int tx = threadIdx.x, ty = threadIdx.y;  // 32 x 8
#pragma unroll
  for (int j = 0; j < 4; ++j)
    tile[ty + j * 8][tx] = ib[(size_t)(r0 + ty + j * 8) * C + c0 + tx];
  __syncthreads();
#pragma unroll
  for (int j = 0; j < 4; ++j)
    out[(size_t)z * ZO + (size_t)(c0 + ty + j * 8) * CS + r0 + tx] =
        f2bf(tile[tx][ty + j * 8]);
}

// ---------------- GEMM1: dual (g,u) + silu*u*c epilogue -> H' bf16 ----------
__global__ __launch_bounds__(256, 2) void gemm1_kernel(
    const u16* __restrict__ Xb, const u16* __restrict__ Wgt,
    const u16* __restrict__ Wut, const float* __restrict__ Cw,
    u16* __restrict__ Hp, int m0) {
  __shared__ u16 sA[128 * 64], sG[128 * 64], sU[128 * 64];
  __shared__ float c_lds[128];
  const int tid = threadIdx.x;
  const int l = tid & 63, w = tid >> 6;
  const int wr = w >> 1, wc = w & 1;
  const int lq = l >> 4, lr = l & 15;
  const int bm = blockIdx.x * 128;   // row offset within M-chunk
  const int nb = blockIdx.y * 128;   // col offset within expert (0..896)
  const int e = blockIdx.z;
  if (tid < 128) c_lds[tid] = Cw[(size_t)(m0 + bm + tid) * 8 + e];
  const u16* gA = Xb + (size_t)(m0 + bm) * 2048;
  const u16* gG = Wgt + (size_t)e * (1024 * 2048) + (size_t)nb * 2048;
  const u16* gU = Wut + (size_t)e * (1024 * 2048) + (size_t)nb * 2048;
  const int sbase = (tid >> 3) * 2048 + (tid & 7) * 8;
  const int lbase = tid * 8;
  f32x4 ag[4][4] = {};
  f32x4 au[4][4] = {};
  for (int kt = 0; kt < 2048; kt += 64) {
#pragma unroll
    for (int i = 0; i < 4; ++i) {
      const int go = sbase + i * (32 * 2048) + kt;
      const int lo = lbase + i * (256 * 8);
      gload16(gA + go, &sA[lo]);
      gload16(gG + go, &sG[lo]);
      gload16(gU + go, &sU[lo]);
    }
    __syncthreads();
#pragma unroll
    for (int kk = 0; kk < 2; ++kk) {
      bf16x8 af[4];
#pragma unroll
      for (int mi = 0; mi < 4; ++mi)
        af[mi] = *(const bf16x8*)&sA[(wr * 64 + mi * 16 + lr) * 64 + kk * 32 + lq * 8];
#pragma unroll
      for (int ni = 0; ni < 4; ++ni) {
        const int boff = (wc * 64 + ni * 16 + lr) * 64 + kk * 32 + lq * 8;
        bf16x8 bg = *(const bf16x8*)&sG[boff];
        bf16x8 bu = *(const bf16x8*)&sU[boff];
#pragma unroll
        for (int mi = 0; mi < 4; ++mi) {
          ag[mi][ni] = __builtin_amdgcn_mfma_f32_16x16x32_bf16(af[mi], bg, ag[mi][ni], 0, 0, 0);
          au[mi][ni] = __builtin_amdgcn_mfma_f32_16x16x32_bf16(af[mi], bu, au[mi][ni], 0, 0, 0);
        }
      }
    }
    __syncthreads();
  }
#pragma unroll
  for (int mi = 0; mi < 4; ++mi) {
#pragma unroll
    for (int ni = 0; ni < 4; ++ni) {
#pragma unroll
      for (int j = 0; j < 4; ++j) {
        const int rl = wr * 64 + mi * 16 + lq * 4 + j;   // C/D: row=(l>>4)*4+j
        const int cl = wc * 64 + ni * 16 + lr;           //      col=l&15
        const float g = ag[mi][ni][j], u = au[mi][ni][j];
        const float h = g * (1.f / (1.f + __expf(-g))) * u * c_lds[rl];
        Hp[(size_t)(bm + rl) * 8192 + (size_t)(e * 1024 + nb + cl)] = f2bf(h);
      }
    }
  }
}

// ---------------- GEMM2: output = H' @ Wd_flat ----------------
__global__ __launch_bounds__(256, 3) void gemm2_kernel(
    const u16* __restrict__ Hp, const u16* __restrict__ Wdt,
    float* __restrict__ out, int m0) {
  __shared__ u16 sA[128 * 64], sB[128 * 64];
  const int tid = threadIdx.x;
  const int l = tid & 63, w = tid >> 6;
  const int wr = w >> 1, wc = w & 1;
  const int lq = l >> 4, lr = l & 15;
  const int bm = blockIdx.x * 128;  // within chunk
  const int nb = blockIdx.y * 128;
  const u16* gA = Hp + (size_t)bm * 8192;
  const u16* gB = Wdt + (size_t)nb * 8192;
  const int sbase = (tid >> 3) * 8192 + (tid & 7) * 8;
  const int lbase = tid * 8;
  f32x4 acc[4][4] = {};
  for (int kt = 0; kt < 8192; kt += 64) {
#pragma unroll
    for (int i = 0; i < 4; ++i) {
      const int go = sbase + i * (32 * 8192) + kt;
      const int lo = lbase + i * (256 * 8);
      gload16(gA + go, &sA[lo]);
      gload16(gB + go, &sB[lo]);
    }
    __syncthreads();
#pragma unroll
    for (int kk = 0; kk < 2; ++kk) {
      bf16x8 af[4];
#pragma unroll
      for (int mi = 0; mi < 4; ++mi)
        af[mi] = *(const bf16x8*)&sA[(wr * 64 + mi * 16 + lr) * 64 + kk * 32 + lq * 8];
#pragma unroll
      for (int ni = 0; ni < 4; ++ni) {
        bf16x8 bfr = *(const bf16x8*)&sB[(wc * 64 + ni * 16 + lr) * 64 + kk * 32 + lq * 8];
#pragma unroll
        for (int mi = 0; mi < 4; ++mi)
          acc[mi][ni] = __builtin_amdgcn_mfma_f32_16x16x32_bf16(af[mi], bfr, acc[mi][ni], 0, 0, 0);
      }
    }
    __syncthreads();
  }
#pragma unroll
  for (int mi = 0; mi < 4; ++mi)
#pragma unroll
    for (int ni = 0; ni < 4; ++ni)
#pragma unroll
      for (int j = 0; j < 4; ++j) {
        const int rl = wr * 64 + mi * 16 + lq * 4 + j;
        const int cl = wc * 64 + ni * 16 + lr;
        out[(size_t)(m0 + bm + rl) * 2048 + (nb + cl)] = acc[mi][ni][j];
      }
}

// ---------------- tension scalar: mean(output^2) ----------------
__global__ __launch_bounds__(256) void sqsum_partial(
    const float* __restrict__ out, float* __restrict__ part, int n4) {
  float s = 0.f;
  const int idx = blockIdx.x * 256 + threadIdx.x;
  const int stride = gridDim.x * 256;
  for (int i = idx; i < n4; i += stride) {
    const float4 v = ((const float4*)out)[i];
    s += v.x * v.x + v.y * v.y + v.z * v.z + v.w * v.w;
  }
#pragma unroll
  for (int off = 32; off > 0; off >>= 1) s += __shfl_down(s, off, 64);
  __shared__ float ls[4];
  if ((threadIdx.x & 63) == 0) ls[threadIdx.x >> 6] = s;
  __syncthreads();
  if (threadIdx.x == 0) part[blockIdx.x] = ls[0] + ls[1] + ls[2] + ls[3];
}

__global__ __launch_bounds__(256) void sqsum_final(
    const float* __restrict__ part, float* __restrict__ dst, int np, float scale) {
  float s = 0.f;
  for (int i = threadIdx.x; i < np; i += 256) s += part[i];
#pragma unroll
  for (int off = 32; off > 0; off >>= 1) s += __shfl_down(s, off, 64);
  __shared__ float ls[4];
  if ((threadIdx.x & 63) == 0) ls[threadIdx.x >> 6] = s;
  __syncthreads();
  if (threadIdx.x == 0) dst[0] = (ls[0] + ls[1] + ls[2] + ls[3]) * scale;
}

// ---------------- launch ----------------
extern "C" void kernel_launch(void* const* d_in, const int* in_sizes, int n_in,
                              void* d_out, int out_size, void* d_ws, size_t ws_size,
                              hipStream_t stream) {
  (void)in_sizes; (void)n_in; (void)out_size; (void)ws_size;
  const float* x  = (const float*)d_in[0];
  const float* Wr = (const float*)d_in[1];
  const float* Wg = (const float*)d_in[2];
  const float* Wu = (const float*)d_in[3];
  const float* Wd = (const float*)d_in[4];
  float* out = (float*)d_out;
  char* ws = (char*)d_ws;
  u16*   Xb   = (u16*)(ws);
  u16*   Wgt  = (u16*)(ws + 33554432);
  u16*   Wut  = (u16*)(ws + 67108864);
  u16*   Wdt  = (u16*)(ws + 100663296);
  u16*   Hp   = (u16*)(ws + 134217728);
  float* Cw   = (float*)(ws + 201326592);
  float* part = (float*)(ws + 201588736);

  router_kernel<<<2048, 256, 0, stream>>>(x, Wr, Cw, Xb);

  dim3 tb(32, 8);
  tcvt_kernel<<<dim3(32, 64, 8), tb, 0, stream>>>(Wg, Wgt, 2048, 1024, 2097152LL, 2048LL);
  tcvt_kernel<<<dim3(32, 64, 8), tb, 0, stream>>>(Wu, Wut, 2048, 1024, 2097152LL, 2048LL);
  tcvt_kernel<<<dim3(64, 32, 8), tb, 0, stream>>>(Wd, Wdt, 1024, 2048, 1024LL, 8192LL);

  for (int ch = 0; ch < 2; ++ch) {
    const int m0 = ch * 4096;
    gemm1_kernel<<<dim3(32, 8, 8), 256, 0, stream>>>(Xb, Wgt, Wut, Cw, Hp, m0);
    gemm2_kernel<<<dim3(32, 16), 256, 0, stream>>>(Hp, Wdt, out, m0);
  }

  sqsum_partial<<<1024, 256, 0, stream>>>(out, part, 16777216 / 4);
  sqsum_final<<<1, 256, 0, stream>>>(part, out + 16777216, 1024, 1.f / 16777216.f);
}